// Round 14
// baseline (334.846 us; speedup 1.0000x reference)
//
#include <hip/hip_runtime.h>
#include <hip/hip_bf16.h>
#include <stdint.h>

typedef unsigned int u32;
typedef unsigned long long u64;
typedef unsigned char u8;
typedef unsigned short u16;

// ---------------------------------------------------------------------------
// Reduction order for n[v] = sum_f image[v,f]^2 bit-matches the XLA:CPU
// reference (H1 tree; vectorized form verified bit-exact, PASS R8-R13).
// ---------------------------------------------------------------------------

// ---- K1: per-vertex squared norm (2 lanes/vertex, float4 loads) ----
__global__ __launch_bounds__(256) void vnorm_kernel(const float* __restrict__ image,
                                                    float* __restrict__ nrm, int V) {
#pragma clang fp contract(off)
  int t = blockIdx.x * 256 + threadIdx.x;
  int v = t >> 1, h = t & 1;
  if (v >= V) return;
  const float4* r4 = (const float4*)(image + (size_t)v * 128) + h;
  float4 a, x;
  x = r4[0];
  a.x = x.x * x.x; a.y = x.y * x.y; a.z = x.z * x.z; a.w = x.w * x.w;
#pragma unroll
  for (int i = 1; i < 16; ++i) {
    x = r4[i * 2];
    a.x = a.x + x.x * x.x; a.y = a.y + x.y * x.y;
    a.z = a.z + x.z * x.z; a.w = a.w + x.w * x.w;
  }
  float bx = __shfl_xor(a.x, 1), by = __shfl_xor(a.y, 1);
  float bz = __shfl_xor(a.z, 1), bw = __shfl_xor(a.w, 1);
  a.x = a.x + bx; a.y = a.y + by; a.z = a.z + bz; a.w = a.w + bw;
  float r0 = a.x + a.z;
  float r1 = a.y + a.w;
  float s = r0 + r1;
  if (h == 0) nrm[v] = s;
}

// ---- K2: per-edge priority, key, boundary + global min/max ----
__global__ __launch_bounds__(256) void edge_kernel(const float* __restrict__ nrm,
                                                   const float* __restrict__ vs,
                                                   const int* __restrict__ edges,
                                                   u64* __restrict__ keysA,
                                                   u8* __restrict__ bnd,
                                                   float* __restrict__ out_sq,
                                                   u32* __restrict__ gmm, int E) {
#pragma clang fp contract(off)
  __shared__ u32 smn[4], smx[4];
  int tid = threadIdx.x;
  int e = blockIdx.x * 256 + tid;
  u32 mn = 0xFFFFFFFFu, mx = 0u;
  if (e < E) {
    int v0 = edges[e], v1 = edges[E + e];
    float sq = nrm[v0] + nrm[v1];
    out_sq[e] = sq;
    u32 sb = __float_as_uint(sq);
    keysA[e] = ((u64)sb << 32) | (u32)e;
    float ax = vs[2 * v0], ay = vs[2 * v0 + 1];
    float bx = vs[2 * v1], by = vs[2 * v1 + 1];
    const float lo = 0.01f, hi = 0.99f;
    bool b = (ax < lo) | (ax > hi) | (ay < lo) | (ay > hi)
           | (bx < lo) | (bx > hi) | (by < lo) | (by > hi);
    bnd[e] = b ? 1 : 0;
    mn = sb; mx = sb;
  }
  int lane = tid & 63, wv = tid >> 6;
#pragma unroll
  for (int d = 32; d >= 1; d >>= 1) {
    u32 a = __shfl_xor(mn, d); mn = (a < mn) ? a : mn;
    u32 b2 = __shfl_xor(mx, d); mx = (b2 > mx) ? b2 : mx;
  }
  if (lane == 0) { smn[wv] = mn; smx[wv] = mx; }
  __syncthreads();
  if (tid == 0) {
    u32 m = smn[0], M = smx[0];
#pragma unroll
    for (int w = 1; w < 4; ++w) {
      if (smn[w] < m) m = smn[w];
      if (smx[w] > M) M = smx[w];
    }
    atomicMin(&gmm[0], m);
    atomicMax(&gmm[1], M);
  }
}

__device__ inline u32 bucket_of(u32 sb, u32 minv, u32 range) {
  return (u32)(((u64)(sb - minv) << 14) / ((u64)range + 1ull));   // 16384 buckets
}

// ---- K3: bucket histogram ----
__global__ __launch_bounds__(256) void hist_kernel(const u64* __restrict__ keysA,
                                                   const u32* __restrict__ gmm,
                                                   u32* __restrict__ ghist, int E) {
  int e = blockIdx.x * 256 + threadIdx.x;
  if (e >= E) return;
  u32 minv = gmm[0], range = gmm[1] - minv;
  u32 b = bucket_of((u32)(keysA[e] >> 32), minv, range);
  atomicAdd(&ghist[b], 1u);
}

// ---- K4: scan of 16384 bucket counts ----
__global__ __launch_bounds__(1024) void scan16k_kernel(const u32* __restrict__ ghist,
                                                       u32* __restrict__ starts,
                                                       u32* __restrict__ cursor, int E) {
  __shared__ u32 wsum[16];
  int tid = threadIdx.x;
  int lane = tid & 63, wv = tid >> 6;
  u32 loc[16];
  u32 s = 0;
#pragma unroll
  for (int i = 0; i < 16; ++i) { loc[i] = ghist[tid * 16 + i]; s += loc[i]; }
  u32 inc = s;
#pragma unroll
  for (int d = 1; d < 64; d <<= 1) {
    u32 t = __shfl_up(inc, d);
    if (lane >= d) inc += t;
  }
  if (lane == 63) wsum[wv] = inc;
  __syncthreads();
  if (tid == 0) {
    u32 r = 0;
#pragma unroll
    for (int w = 0; w < 16; ++w) { u32 t = wsum[w]; wsum[w] = r; r += t; }
  }
  __syncthreads();
  u32 run = wsum[wv] + (inc - s);
#pragma unroll
  for (int i = 0; i < 16; ++i) {
    starts[tid * 16 + i] = run;
    cursor[tid * 16 + i] = run;
    run += loc[i];
  }
  if (tid == 0) starts[16384] = (u32)E;
}

// ---- K5: scatter keys into bucket slots ----
__global__ __launch_bounds__(256) void scatter_kernel(const u64* __restrict__ keysA,
                                                      const u32* __restrict__ gmm,
                                                      u32* __restrict__ cursor,
                                                      u64* __restrict__ keysB, int E) {
  int e = blockIdx.x * 256 + threadIdx.x;
  if (e >= E) return;
  u64 key = keysA[e];
  u32 minv = gmm[0], range = gmm[1] - minv;
  u32 b = bucket_of((u32)(key >> 32), minv, range);
  u32 pos = atomicAdd(&cursor[b], 1u);
  keysB[pos] = key;
}

// ---- K6: per-bucket 128-elem bitonic sort (1 wave/bucket) + pack write ----
__global__ __launch_bounds__(256) void bucketsort_kernel(const u64* __restrict__ keysB,
                                                         const u32* __restrict__ starts,
                                                         const int* __restrict__ edges,
                                                         const u8* __restrict__ bnd,
                                                         u64* __restrict__ pack,
                                                         int E, int V, int NpadB) {
  int tid = threadIdx.x;
  int lane = tid & 63;
  int w = blockIdx.x * 4 + (tid >> 6);           // bucket id
  u32 start = starts[w];
  int cnt = (int)(starts[w + 1] - start);
  if (cnt > 128) cnt = 128;                      // safety clamp (P ~ 0)
  u64 k0 = (lane < cnt) ? keysB[start + lane] : ~0ull;
  u64 k1 = (64 + lane < cnt) ? keysB[start + 64 + lane] : ~0ull;
  int idx0 = lane * 2, idx1 = lane * 2 + 1;
#pragma unroll
  for (int k = 2; k <= 128; k <<= 1) {
#pragma unroll
    for (int j = 64; j >= 1; j >>= 1) {
      if (j > k / 2) continue;
      if (j >= 2) {
        int lj = j >> 1;
        u64 p0 = __shfl_xor(k0, lj);
        u64 p1 = __shfl_xor(k1, lj);
        bool keepMin0 = (((idx0 & j) == 0) == ((idx0 & k) == 0));
        k0 = keepMin0 ? (k0 < p0 ? k0 : p0) : (k0 > p0 ? k0 : p0);
        k1 = keepMin0 ? (k1 < p1 ? k1 : p1) : (k1 > p1 ? k1 : p1);
      } else {
        bool up = ((idx0 & k) == 0);
        u64 mn = (k0 < k1) ? k0 : k1;
        u64 mx = (k0 < k1) ? k1 : k0;
        k0 = up ? mn : mx;
        k1 = up ? mx : mn;
      }
    }
  }
  if (idx0 < cnt) {
    u32 id = (u32)k0;
    int vv0 = edges[id], vv1 = edges[E + id];
    pack[start + idx0] = (u64)(u32)(vv0 | (vv1 << 16)) | ((u64)bnd[id] << 32);
  }
  if (idx1 < cnt) {
    u32 id = (u32)k1;
    int vv0 = edges[id], vv1 = edges[E + id];
    pack[start + idx1] = (u64)(u32)(vv0 | (vv1 << 16)) | ((u64)bnd[id] << 32);
  }
  // sentinel tail [E, NpadB): nb=1 (never kills), verts in [V, V+512)
  int g = blockIdx.x * 256 + tid;
  int i = E + g;
  if (i < NpadB) {
    u32 sv0 = (u32)V + (((u32)i & 255u) << 1);
    pack[i] = (u64)(sv0 | ((sv0 + 1) << 16)) | (1ull << 32);
  }
}

// ---- K7: exact greedy collapse, ordered 8192-edge batches + in-reg peel ---
// R12/R13-verified decision logic; 512 threads x 16 slots (pos = s*512+tid):
//   tUK[v] = min over und|kill batch edges targeting v of (pos<<1)|isUnd.
//   und e: earlier KILL at v0|v1 -> NOKILL; no earlier und|kill at v0 AND
//   min at v1 -> KILL; else wait. Earliest undecided always decides.
// Status held as packed u32 masks; pk[]/pn[] fully unrolled (static idx).
// Threshold post-hoc per batch: rank kills by pos, apply first `remaining`.
__device__ inline void lds_min_u16(u16* tarr, int idx, u16 val) {
  u32* w = (u32*)(tarr + (idx & ~1));
  int sh = (idx & 1) * 16;
  u32 old = *w;
  while (true) {
    u32 cur = (old >> sh) & 0xffffu;
    if ((u32)val >= cur) break;
    u32 nv = (old & ~(0xffffu << sh)) | ((u32)val << sh);
    u32 prev = atomicCAS(w, old, nv);
    if (prev == old) break;
    old = prev;
  }
}

#define TPB 512
#define SLOTS 16
#define NBAT 8192

__global__ __launch_bounds__(512) void batch_kernel(const u64* __restrict__ pack,
                                                    const int* __restrict__ tgt,
                                                    float* __restrict__ out,
                                                    int V, int E, int NpadB) {
  __shared__ u16 tUK[50560];     // 101 KB; covers sentinel verts < V+512
  __shared__ u32 alive[1600];
  __shared__ u32 wred[129];
  __shared__ u32 misc[4];
  int tid = threadIdx.x;
  int lane = tid & 63, wv = tid >> 6;          // wv in 0..7
  for (int i = tid; i < 1600; i += TPB) alive[i] = 0xFFFFFFFFu;
  for (int i = tid; i < 25280; i += TPB) ((u32*)tUK)[i] = 0xFFFFFFFFu;
  if (tid < 4) misc[tid] = 0u;
  int target = tgt[0];
  int needed = V - target; if (needed < 0) needed = 0;
  int remaining = needed;
  __syncthreads();
  int nbatch = NpadB / NBAT;
  u64 pk[SLOTS], pn[SLOTS];
#pragma unroll
  for (int s = 0; s < SLOTS; ++s) pk[s] = pack[s * TPB + tid];
  for (int b = 0; b < nbatch; ++b) {
    if (remaining <= 0) break;
    const u64* np = pack + (size_t)((b + 1 < nbatch) ? (b + 1) : b) * NBAT;
#pragma unroll
    for (int s = 0; s < SLOTS; ++s) pn[s] = np[s * TPB + tid];
    // ---- init status masks from current alive ----
    u32 und = 0, kill = 0;
#pragma unroll
    for (int s = 0; s < SLOTS; ++s) {
      int v0 = (int)(pk[s] & 0xffff), v1 = (int)((pk[s] >> 16) & 0xffff);
      int nb_ = (int)((pk[s] >> 32) & 1);
      int a0 = (int)((alive[v0 >> 5] >> (v0 & 31)) & 1);
      int a1 = (int)((alive[v1 >> 5] >> (v1 & 31)) & 1);
      und |= (u32)(a0 & a1 & (nb_ ^ 1)) << s;
    }
    // ---- peel rounds ----
    for (int r = 0; r < 9000; ++r) {
#pragma unroll
      for (int s = 0; s < SLOTS; ++s) {
        if ((und | kill) & (1u << s)) {
          int v1 = (int)((pk[s] >> 16) & 0xffff);
          u32 pos = (u32)(s * TPB + tid);
          lds_min_u16(tUK, v1, (u16)((pos << 1) | ((und >> s) & 1)));
        }
      }
      __syncthreads();                                   // B1: posts visible
#pragma unroll
      for (int s = 0; s < SLOTS; ++s) {
        if (und & (1u << s)) {
          int v0 = (int)(pk[s] & 0xffff), v1 = (int)((pk[s] >> 16) & 0xffff);
          u32 my = (((u32)(s * TPB + tid)) << 1) | 1u;
          u32 b0v = (v0 == v1) ? 0xFFFFu : (u32)tUK[v0];
          u32 b1v = (u32)tUK[v1];
          int ek = (int)(((b0v < my) & ((b0v & 1u) ^ 1u)) |
                         ((b1v < my) & ((b1v & 1u) ^ 1u)));
          int nk = (int)(b0v > my) & (int)(b1v == my) & (ek ^ 1);
          kill |= (u32)nk << s;
          if (nk | ek) und &= ~(1u << s);
        }
      }
      u64 au = __ballot(und != 0u);
      if (lane == 0 && au) atomicOr(&misc[r & 3], 1u);
      if (tid == 0) misc[(r + 2) & 3] = 0u;              // recycle slot r+2
      __syncthreads();                                   // B2: reads done
#pragma unroll
      for (int s = 0; s < SLOTS; ++s) {
        int v1 = (int)((pk[s] >> 16) & 0xffff);
        tUK[v1] = 0xFFFF;                                // reset touched
      }
      u32 anyu = misc[r & 3];
      __syncthreads();                                   // B3: resets visible
      if (anyu == 0u) break;
    }
    // ---- rank kills in position order, apply first `remaining` ----
#pragma unroll
    for (int s = 0; s < SLOTS; ++s) {
      u64 km = __ballot((kill >> s) & 1);
      if (lane == 0) wred[s * 8 + wv] = (u32)__popcll(km);
    }
    if (tid < 4) misc[tid] = 0u;                         // clean for next batch
    __syncthreads();                                     // B4
    if (tid == 0) {
      u32 run = 0;
      for (int i = 0; i < 128; ++i) { u32 t2 = wred[i]; wred[i] = run; run += t2; }
      wred[128] = run;
    }
    __syncthreads();                                     // B5
    u32 K = wred[128];
#pragma unroll
    for (int s = 0; s < SLOTS; ++s) {
      u64 km = __ballot((kill >> s) & 1);
      if ((kill >> s) & 1) {
        u32 rank = wred[s * 8 + wv] + (u32)__popcll(km & ((1ull << lane) - 1ull));
        if (rank < (u32)remaining) {
          int v1 = (int)((pk[s] >> 16) & 0xffff);
          atomicAnd(&alive[v1 >> 5], ~(1u << (v1 & 31)));
        }
      }
    }
    remaining -= (int)((K < (u32)remaining) ? K : (u32)remaining);
    __syncthreads();                                     // B6: applies visible
#pragma unroll
    for (int s = 0; s < SLOTS; ++s) pk[s] = pn[s];
  }
  // ---- fused expand: write float mask + count directly ----
  for (int i = tid; i < V; i += TPB)
    out[E + i] = ((alive[i >> 5] >> (i & 31)) & 1) ? 1.0f : 0.0f;
  if (tid == 0) out[E + V] = (float)(V - (needed - remaining));
}

extern "C" void kernel_launch(void* const* d_in, const int* in_sizes, int n_in,
                              void* d_out, int out_size, void* d_ws, size_t ws_size,
                              hipStream_t stream) {
  const float* image = (const float*)d_in[0];
  const float* vs    = (const float*)d_in[1];
  const int*   edges = (const int*)d_in[2];
  const int*   tgt   = (const int*)d_in[3];
  int V = in_sizes[1] / 2;                 // 50000
  int E = in_sizes[2] / 2;                 // 150000
  int NpadB = ((E + NBAT - 1) / NBAT) * NBAT;   // 155648 (19 x 8192)

  char* ws = (char*)d_ws;
  size_t o = 0;
  u64* keysA  = (u64*)(ws + o); o += (size_t)E * 8;
  u64* keysB  = (u64*)(ws + o); o += (size_t)E * 8;
  u64* pack   = (u64*)(ws + o); o += (size_t)NpadB * 8;
  float* nrm  = (float*)(ws + o); o += (size_t)V * 4;
  u8*  bnd    = (u8*)(ws + o);  o += (size_t)E;
  o = (o + 255) & ~(size_t)255;
  u32* ghist  = (u32*)(ws + o); o += 16384 * 4;
  u32* starts = (u32*)(ws + o); o += 16385 * 4;
  u32* cursor = (u32*)(ws + o); o += 16384 * 4;
  u32* gmm    = (u32*)(ws + o); o += 256;
  float* out = (float*)d_out;

  (void)hipMemsetAsync(ghist, 0, 16384 * 4, stream);
  (void)hipMemsetAsync(&gmm[0], 0xFF, 4, stream);   // min = 0xFFFFFFFF
  (void)hipMemsetAsync(&gmm[1], 0x00, 4, stream);   // max = 0

  int eb = (E + 255) / 256;
  vnorm_kernel<<<dim3((2 * V + 255) / 256), dim3(256), 0, stream>>>(image, nrm, V);
  edge_kernel<<<dim3(eb), dim3(256), 0, stream>>>(nrm, vs, edges, keysA, bnd, out, gmm, E);
  hist_kernel<<<dim3(eb), dim3(256), 0, stream>>>(keysA, gmm, ghist, E);
  scan16k_kernel<<<dim3(1), dim3(1024), 0, stream>>>(ghist, starts, cursor, E);
  scatter_kernel<<<dim3(eb), dim3(256), 0, stream>>>(keysA, gmm, cursor, keysB, E);
  bucketsort_kernel<<<dim3(4096), dim3(256), 0, stream>>>(keysB, starts, edges, bnd,
                                                          pack, E, V, NpadB);
  batch_kernel<<<dim3(1), dim3(512), 0, stream>>>(pack, tgt, out, V, E, NpadB);
}

// Round 15
// 254.483 us; speedup vs baseline: 1.3158x; 1.3158x over previous
//
#include <hip/hip_runtime.h>
#include <hip/hip_bf16.h>
#include <stdint.h>

typedef unsigned int u32;
typedef unsigned long long u64;
typedef unsigned char u8;
typedef unsigned short u16;

// ---------------------------------------------------------------------------
// Reduction order for n[v] = sum_f image[v,f]^2 bit-matches the XLA:CPU
// reference (H1 tree; vectorized form verified bit-exact, PASS R8-R14).
// ---------------------------------------------------------------------------

// ---- K1: per-vertex squared norm (2 lanes/vertex, float4 loads) ----------
// Also zero-inits ghist and gmm (folds 3 memset dispatches into this one).
__global__ __launch_bounds__(256) void vnorm_kernel(const float* __restrict__ image,
                                                    float* __restrict__ nrm,
                                                    u32* __restrict__ ghist,
                                                    u32* __restrict__ gmm, int V) {
#pragma clang fp contract(off)
  int t = blockIdx.x * 256 + threadIdx.x;
  for (int i = t; i < 16384; i += gridDim.x * 256) ghist[i] = 0u;
  if (t == 0) { gmm[0] = 0xFFFFFFFFu; gmm[1] = 0u; }
  int v = t >> 1, h = t & 1;
  if (v >= V) return;
  const float4* r4 = (const float4*)(image + (size_t)v * 128) + h;
  float4 a, x;
  x = r4[0];
  a.x = x.x * x.x; a.y = x.y * x.y; a.z = x.z * x.z; a.w = x.w * x.w;
#pragma unroll
  for (int i = 1; i < 16; ++i) {
    x = r4[i * 2];
    a.x = a.x + x.x * x.x; a.y = a.y + x.y * x.y;
    a.z = a.z + x.z * x.z; a.w = a.w + x.w * x.w;
  }
  float bx = __shfl_xor(a.x, 1), by = __shfl_xor(a.y, 1);
  float bz = __shfl_xor(a.z, 1), bw = __shfl_xor(a.w, 1);
  a.x = a.x + bx; a.y = a.y + by; a.z = a.z + bz; a.w = a.w + bw;
  float r0 = a.x + a.z;
  float r1 = a.y + a.w;
  float s = r0 + r1;
  if (h == 0) nrm[v] = s;
}

// ---- K2: per-edge priority, key, boundary + global min/max ----
__global__ __launch_bounds__(256) void edge_kernel(const float* __restrict__ nrm,
                                                   const float* __restrict__ vs,
                                                   const int* __restrict__ edges,
                                                   u64* __restrict__ keysA,
                                                   u8* __restrict__ bnd,
                                                   float* __restrict__ out_sq,
                                                   u32* __restrict__ gmm, int E) {
#pragma clang fp contract(off)
  __shared__ u32 smn[4], smx[4];
  int tid = threadIdx.x;
  int e = blockIdx.x * 256 + tid;
  u32 mn = 0xFFFFFFFFu, mx = 0u;
  if (e < E) {
    int v0 = edges[e], v1 = edges[E + e];
    float sq = nrm[v0] + nrm[v1];
    out_sq[e] = sq;
    u32 sb = __float_as_uint(sq);
    keysA[e] = ((u64)sb << 32) | (u32)e;
    float ax = vs[2 * v0], ay = vs[2 * v0 + 1];
    float bx = vs[2 * v1], by = vs[2 * v1 + 1];
    const float lo = 0.01f, hi = 0.99f;
    bool b = (ax < lo) | (ax > hi) | (ay < lo) | (ay > hi)
           | (bx < lo) | (bx > hi) | (by < lo) | (by > hi);
    bnd[e] = b ? 1 : 0;
    mn = sb; mx = sb;
  }
  int lane = tid & 63, wv = tid >> 6;
#pragma unroll
  for (int d = 32; d >= 1; d >>= 1) {
    u32 a = __shfl_xor(mn, d); mn = (a < mn) ? a : mn;
    u32 b2 = __shfl_xor(mx, d); mx = (b2 > mx) ? b2 : mx;
  }
  if (lane == 0) { smn[wv] = mn; smx[wv] = mx; }
  __syncthreads();
  if (tid == 0) {
    u32 m = smn[0], M = smx[0];
#pragma unroll
    for (int w = 1; w < 4; ++w) {
      if (smn[w] < m) m = smn[w];
      if (smx[w] > M) M = smx[w];
    }
    atomicMin(&gmm[0], m);
    atomicMax(&gmm[1], M);
  }
}

__device__ inline u32 bucket_of(u32 sb, u32 minv, u32 range) {
  return (u32)(((u64)(sb - minv) << 14) / ((u64)range + 1ull));   // 16384 buckets
}

// ---- K3: bucket histogram ----
__global__ __launch_bounds__(256) void hist_kernel(const u64* __restrict__ keysA,
                                                   const u32* __restrict__ gmm,
                                                   u32* __restrict__ ghist, int E) {
  int e = blockIdx.x * 256 + threadIdx.x;
  if (e >= E) return;
  u32 minv = gmm[0], range = gmm[1] - minv;
  u32 b = bucket_of((u32)(keysA[e] >> 32), minv, range);
  atomicAdd(&ghist[b], 1u);
}

// ---- K4: scan of 16384 bucket counts ----
__global__ __launch_bounds__(1024) void scan16k_kernel(const u32* __restrict__ ghist,
                                                       u32* __restrict__ starts,
                                                       u32* __restrict__ cursor, int E) {
  __shared__ u32 wsum[16];
  int tid = threadIdx.x;
  int lane = tid & 63, wv = tid >> 6;
  u32 loc[16];
  u32 s = 0;
#pragma unroll
  for (int i = 0; i < 16; ++i) { loc[i] = ghist[tid * 16 + i]; s += loc[i]; }
  u32 inc = s;
#pragma unroll
  for (int d = 1; d < 64; d <<= 1) {
    u32 t = __shfl_up(inc, d);
    if (lane >= d) inc += t;
  }
  if (lane == 63) wsum[wv] = inc;
  __syncthreads();
  if (tid == 0) {
    u32 r = 0;
#pragma unroll
    for (int w = 0; w < 16; ++w) { u32 t = wsum[w]; wsum[w] = r; r += t; }
  }
  __syncthreads();
  u32 run = wsum[wv] + (inc - s);
#pragma unroll
  for (int i = 0; i < 16; ++i) {
    starts[tid * 16 + i] = run;
    cursor[tid * 16 + i] = run;
    run += loc[i];
  }
  if (tid == 0) starts[16384] = (u32)E;
}

// ---- K5: scatter keys into bucket slots ----
__global__ __launch_bounds__(256) void scatter_kernel(const u64* __restrict__ keysA,
                                                      const u32* __restrict__ gmm,
                                                      u32* __restrict__ cursor,
                                                      u64* __restrict__ keysB, int E) {
  int e = blockIdx.x * 256 + threadIdx.x;
  if (e >= E) return;
  u64 key = keysA[e];
  u32 minv = gmm[0], range = gmm[1] - minv;
  u32 b = bucket_of((u32)(key >> 32), minv, range);
  u32 pos = atomicAdd(&cursor[b], 1u);
  keysB[pos] = key;
}

// ---- K6: per-bucket 128-elem bitonic sort (1 wave/bucket) + pack write ----
__global__ __launch_bounds__(256) void bucketsort_kernel(const u64* __restrict__ keysB,
                                                         const u32* __restrict__ starts,
                                                         const int* __restrict__ edges,
                                                         const u8* __restrict__ bnd,
                                                         u64* __restrict__ pack,
                                                         int E, int V, int NpadB) {
  int tid = threadIdx.x;
  int lane = tid & 63;
  int w = blockIdx.x * 4 + (tid >> 6);           // bucket id
  u32 start = starts[w];
  int cnt = (int)(starts[w + 1] - start);
  if (cnt > 128) cnt = 128;                      // safety clamp (P ~ 0)
  u64 k0 = (lane < cnt) ? keysB[start + lane] : ~0ull;
  u64 k1 = (64 + lane < cnt) ? keysB[start + 64 + lane] : ~0ull;
  int idx0 = lane * 2, idx1 = lane * 2 + 1;
#pragma unroll
  for (int k = 2; k <= 128; k <<= 1) {
#pragma unroll
    for (int j = 64; j >= 1; j >>= 1) {
      if (j > k / 2) continue;
      if (j >= 2) {
        int lj = j >> 1;
        u64 p0 = __shfl_xor(k0, lj);
        u64 p1 = __shfl_xor(k1, lj);
        bool keepMin0 = (((idx0 & j) == 0) == ((idx0 & k) == 0));
        k0 = keepMin0 ? (k0 < p0 ? k0 : p0) : (k0 > p0 ? k0 : p0);
        k1 = keepMin0 ? (k1 < p1 ? k1 : p1) : (k1 > p1 ? k1 : p1);
      } else {
        bool up = ((idx0 & k) == 0);
        u64 mn = (k0 < k1) ? k0 : k1;
        u64 mx = (k0 < k1) ? k1 : k0;
        k0 = up ? mn : mx;
        k1 = up ? mx : mn;
      }
    }
  }
  if (idx0 < cnt) {
    u32 id = (u32)k0;
    int vv0 = edges[id], vv1 = edges[E + id];
    pack[start + idx0] = (u64)(u32)(vv0 | (vv1 << 16)) | ((u64)bnd[id] << 32);
  }
  if (idx1 < cnt) {
    u32 id = (u32)k1;
    int vv0 = edges[id], vv1 = edges[E + id];
    pack[start + idx1] = (u64)(u32)(vv0 | (vv1 << 16)) | ((u64)bnd[id] << 32);
  }
  // sentinel tail [E, NpadB): nb=1 (never kills), verts in [V, V+512)
  int g = blockIdx.x * 256 + tid;
  int i = E + g;
  if (i < NpadB) {
    u32 sv0 = (u32)V + (((u32)i & 255u) << 1);
    pack[i] = (u64)(sv0 | ((sv0 + 1) << 16)) | (1ull << 32);
  }
}

// ---- K7: exact greedy collapse, ordered 4096-edge batches + in-reg peel ---
// R12/R13-verified decision logic; 1024 threads x 4 slots (pos = s*1024+tid).
// NEW: version-tagged tUK entries kill the per-round reset phase:
//   u16 = [15:13] verTag | [12:1] pos | [0] isUnd, verTag = 6 - (round%7)
//   (DECREASING per round -> stale entries always lose the CAS-min; readers
//   validate tag else treat as empty; full wipe once per 7-round cycle).
// 2 barriers/round instead of 3.
__device__ inline void lds_min_u16(u16* tarr, int idx, u16 val) {
  u32* w = (u32*)(tarr + (idx & ~1));
  int sh = (idx & 1) * 16;
  u32 old = *w;
  while (true) {
    u32 cur = (old >> sh) & 0xffffu;
    if ((u32)val >= cur) break;
    u32 nv = (old & ~(0xffffu << sh)) | ((u32)val << sh);
    u32 prev = atomicCAS(w, old, nv);
    if (prev == old) break;
    old = prev;
  }
}

#define TPB 1024
#define SLOTS 4
#define NBAT 4096

__global__ __launch_bounds__(1024) void batch_kernel(const u64* __restrict__ pack,
                                                     const int* __restrict__ tgt,
                                                     float* __restrict__ out,
                                                     int V, int E, int NpadB) {
  __shared__ u16 tUK[50560];     // 101 KB; covers sentinel verts < V+512
  __shared__ u32 alive[1600];
  __shared__ u32 wred[65];
  __shared__ u32 misc[4];
  int tid = threadIdx.x;
  int lane = tid & 63, wv = tid >> 6;
  for (int i = tid; i < 1600; i += TPB) alive[i] = 0xFFFFFFFFu;
  if (tid < 4) misc[tid] = 0u;
  int target = tgt[0];
  int needed = V - target; if (needed < 0) needed = 0;
  int remaining = needed;
  int nbatch = NpadB / NBAT;
  u64 pk[SLOTS], pn[SLOTS];
#pragma unroll
  for (int s = 0; s < SLOTS; ++s) pk[s] = pack[s * TPB + tid];
  // batch-start wipe below doubles as the init barrier
  for (int b = 0; b < nbatch; ++b) {
    if (remaining <= 0) break;
    const u64* np = pack + (size_t)((b + 1 < nbatch) ? (b + 1) : b) * NBAT;
#pragma unroll
    for (int s = 0; s < SLOTS; ++s) pn[s] = np[s * TPB + tid];
    // ---- wipe tUK (fresh verTag cycle) ----
    for (int i = tid; i < 25280; i += TPB) ((u32*)tUK)[i] = 0xFFFFFFFFu;
    __syncthreads();                                     // W: wipe + alive visible
    // ---- init status masks from current alive ----
    u32 und = 0, kill = 0;
#pragma unroll
    for (int s = 0; s < SLOTS; ++s) {
      int v0 = (int)(pk[s] & 0xffff), v1 = (int)((pk[s] >> 16) & 0xffff);
      int nb_ = (int)((pk[s] >> 32) & 1);
      int a0 = (int)((alive[v0 >> 5] >> (v0 & 31)) & 1);
      int a1 = (int)((alive[v1 >> 5] >> (v1 & 31)) & 1);
      und |= (u32)(a0 & a1 & (nb_ ^ 1)) << s;
    }
    // ---- peel rounds: 2 barriers each (no reset phase) ----
    int rc = 0;
    for (int r = 0; r < 4200; ++r) {
      u32 tag = (u32)(6 - rc);
#pragma unroll
      for (int s = 0; s < SLOTS; ++s) {
        if ((und | kill) & (1u << s)) {
          int v1 = (int)((pk[s] >> 16) & 0xffff);
          u32 pos = (u32)(s * TPB + tid);
          lds_min_u16(tUK, v1, (u16)((tag << 13) | (pos << 1) | ((und >> s) & 1)));
        }
      }
      __syncthreads();                                   // B1: posts visible
#pragma unroll
      for (int s = 0; s < SLOTS; ++s) {
        if (und & (1u << s)) {
          int v0 = (int)(pk[s] & 0xffff), v1 = (int)((pk[s] >> 16) & 0xffff);
          u32 my = (tag << 13) | (((u32)(s * TPB + tid)) << 1) | 1u;
          u32 raw0 = (u32)tUK[v0], raw1 = (u32)tUK[v1];
          u32 b0v = (v0 == v1) ? 0xFFFFu : ((raw0 >> 13) == tag ? raw0 : 0xFFFFu);
          u32 b1v = ((raw1 >> 13) == tag) ? raw1 : 0xFFFFu;
          int ek = (int)(((b0v < my) & ((b0v & 1u) ^ 1u)) |
                         ((b1v < my) & ((b1v & 1u) ^ 1u)));
          int nk = (int)(b0v > my) & (int)(b1v == my) & (ek ^ 1);
          kill |= (u32)nk << s;
          if (nk | ek) und &= ~(1u << s);
        }
      }
      u64 au = __ballot(und != 0u);
      if (lane == 0 && au) atomicOr(&misc[r & 3], 1u);
      if (tid == 0) misc[(r + 2) & 3] = 0u;              // recycle slot r+2
      __syncthreads();                                   // B2: reads done
      u32 anyu = misc[r & 3];
      if (anyu == 0u) break;
      if (++rc == 7) {                                   // verTag cycle wrap
        for (int i = tid; i < 25280; i += TPB) ((u32*)tUK)[i] = 0xFFFFFFFFu;
        __syncthreads();                                 // wipe visible
        rc = 0;
      }
    }
    // ---- rank kills in position order, apply first `remaining` ----
#pragma unroll
    for (int s = 0; s < SLOTS; ++s) {
      u64 km = __ballot((kill >> s) & 1);
      if (lane == 0) wred[s * 16 + wv] = (u32)__popcll(km);
    }
    if (tid < 4) misc[tid] = 0u;                         // clean for next batch
    __syncthreads();                                     // B4
    if (tid == 0) {
      u32 run = 0;
      for (int i = 0; i < 64; ++i) { u32 t2 = wred[i]; wred[i] = run; run += t2; }
      wred[64] = run;
    }
    __syncthreads();                                     // B5
    u32 K = wred[64];
#pragma unroll
    for (int s = 0; s < SLOTS; ++s) {
      u64 km = __ballot((kill >> s) & 1);
      if ((kill >> s) & 1) {
        u32 rank = wred[s * 16 + wv] + (u32)__popcll(km & ((1ull << lane) - 1ull));
        if (rank < (u32)remaining) {
          int v1 = (int)((pk[s] >> 16) & 0xffff);
          atomicAnd(&alive[v1 >> 5], ~(1u << (v1 & 31)));
        }
      }
    }
    remaining -= (int)((K < (u32)remaining) ? K : (u32)remaining);
    // next iteration's wipe barrier orders applies before alive reads
#pragma unroll
    for (int s = 0; s < SLOTS; ++s) pk[s] = pn[s];
  }
  __syncthreads();                                       // final applies visible
  // ---- fused expand: write float mask + count directly ----
  for (int i = tid; i < V; i += TPB)
    out[E + i] = ((alive[i >> 5] >> (i & 31)) & 1) ? 1.0f : 0.0f;
  if (tid == 0) out[E + V] = (float)(V - (needed - remaining));
}

extern "C" void kernel_launch(void* const* d_in, const int* in_sizes, int n_in,
                              void* d_out, int out_size, void* d_ws, size_t ws_size,
                              hipStream_t stream) {
  const float* image = (const float*)d_in[0];
  const float* vs    = (const float*)d_in[1];
  const int*   edges = (const int*)d_in[2];
  const int*   tgt   = (const int*)d_in[3];
  int V = in_sizes[1] / 2;                 // 50000
  int E = in_sizes[2] / 2;                 // 150000
  int NpadB = ((E + NBAT - 1) / NBAT) * NBAT;   // 151552 (37 x 4096)

  char* ws = (char*)d_ws;
  size_t o = 0;
  u64* keysA  = (u64*)(ws + o); o += (size_t)E * 8;
  u64* keysB  = (u64*)(ws + o); o += (size_t)E * 8;
  u64* pack   = (u64*)(ws + o); o += (size_t)NpadB * 8;
  float* nrm  = (float*)(ws + o); o += (size_t)V * 4;
  u8*  bnd    = (u8*)(ws + o);  o += (size_t)E;
  o = (o + 255) & ~(size_t)255;
  u32* ghist  = (u32*)(ws + o); o += 16384 * 4;
  u32* starts = (u32*)(ws + o); o += 16385 * 4;
  u32* cursor = (u32*)(ws + o); o += 16384 * 4;
  u32* gmm    = (u32*)(ws + o); o += 256;
  float* out = (float*)d_out;

  int eb = (E + 255) / 256;
  vnorm_kernel<<<dim3((2 * V + 255) / 256), dim3(256), 0, stream>>>(image, nrm, ghist, gmm, V);
  edge_kernel<<<dim3(eb), dim3(256), 0, stream>>>(nrm, vs, edges, keysA, bnd, out, gmm, E);
  hist_kernel<<<dim3(eb), dim3(256), 0, stream>>>(keysA, gmm, ghist, E);
  scan16k_kernel<<<dim3(1), dim3(1024), 0, stream>>>(ghist, starts, cursor, E);
  scatter_kernel<<<dim3(eb), dim3(256), 0, stream>>>(keysA, gmm, cursor, keysB, E);
  bucketsort_kernel<<<dim3(4096), dim3(256), 0, stream>>>(keysB, starts, edges, bnd,
                                                          pack, E, V, NpadB);
  batch_kernel<<<dim3(1), dim3(1024), 0, stream>>>(pack, tgt, out, V, E, NpadB);
}

// Round 16
// 235.718 us; speedup vs baseline: 1.4205x; 1.0796x over previous
//
#include <hip/hip_runtime.h>
#include <hip/hip_bf16.h>
#include <stdint.h>

typedef unsigned int u32;
typedef unsigned long long u64;
typedef unsigned char u8;
typedef unsigned short u16;

// ---------------------------------------------------------------------------
// Reduction order for n[v] = sum_f image[v,f]^2 bit-matches the XLA:CPU
// reference (H1 tree; vectorized form verified bit-exact, PASS R8-R15).
// ---------------------------------------------------------------------------

// ---- K1: per-vertex squared norm (2 lanes/vertex, float4 loads) ----------
// Also zero-inits ghist and gmm (folds 3 memset dispatches into this one).
__global__ __launch_bounds__(256) void vnorm_kernel(const float* __restrict__ image,
                                                    float* __restrict__ nrm,
                                                    u32* __restrict__ ghist,
                                                    u32* __restrict__ gmm, int V) {
#pragma clang fp contract(off)
  int t = blockIdx.x * 256 + threadIdx.x;
  for (int i = t; i < 16384; i += gridDim.x * 256) ghist[i] = 0u;
  if (t == 0) { gmm[0] = 0xFFFFFFFFu; gmm[1] = 0u; }
  int v = t >> 1, h = t & 1;
  if (v >= V) return;
  const float4* r4 = (const float4*)(image + (size_t)v * 128) + h;
  float4 a, x;
  x = r4[0];
  a.x = x.x * x.x; a.y = x.y * x.y; a.z = x.z * x.z; a.w = x.w * x.w;
#pragma unroll
  for (int i = 1; i < 16; ++i) {
    x = r4[i * 2];
    a.x = a.x + x.x * x.x; a.y = a.y + x.y * x.y;
    a.z = a.z + x.z * x.z; a.w = a.w + x.w * x.w;
  }
  float bx = __shfl_xor(a.x, 1), by = __shfl_xor(a.y, 1);
  float bz = __shfl_xor(a.z, 1), bw = __shfl_xor(a.w, 1);
  a.x = a.x + bx; a.y = a.y + by; a.z = a.z + bz; a.w = a.w + bw;
  float r0 = a.x + a.z;
  float r1 = a.y + a.w;
  float s = r0 + r1;
  if (h == 0) nrm[v] = s;
}

// ---- K2: per-edge priority, key, boundary + global min/max ----
__global__ __launch_bounds__(256) void edge_kernel(const float* __restrict__ nrm,
                                                   const float* __restrict__ vs,
                                                   const int* __restrict__ edges,
                                                   u64* __restrict__ keysA,
                                                   u8* __restrict__ bnd,
                                                   float* __restrict__ out_sq,
                                                   u32* __restrict__ gmm, int E) {
#pragma clang fp contract(off)
  __shared__ u32 smn[4], smx[4];
  int tid = threadIdx.x;
  int e = blockIdx.x * 256 + tid;
  u32 mn = 0xFFFFFFFFu, mx = 0u;
  if (e < E) {
    int v0 = edges[e], v1 = edges[E + e];
    float sq = nrm[v0] + nrm[v1];
    out_sq[e] = sq;
    u32 sb = __float_as_uint(sq);
    keysA[e] = ((u64)sb << 32) | (u32)e;
    float ax = vs[2 * v0], ay = vs[2 * v0 + 1];
    float bx = vs[2 * v1], by = vs[2 * v1 + 1];
    const float lo = 0.01f, hi = 0.99f;
    bool b = (ax < lo) | (ax > hi) | (ay < lo) | (ay > hi)
           | (bx < lo) | (bx > hi) | (by < lo) | (by > hi);
    bnd[e] = b ? 1 : 0;
    mn = sb; mx = sb;
  }
  int lane = tid & 63, wv = tid >> 6;
#pragma unroll
  for (int d = 32; d >= 1; d >>= 1) {
    u32 a = __shfl_xor(mn, d); mn = (a < mn) ? a : mn;
    u32 b2 = __shfl_xor(mx, d); mx = (b2 > mx) ? b2 : mx;
  }
  if (lane == 0) { smn[wv] = mn; smx[wv] = mx; }
  __syncthreads();
  if (tid == 0) {
    u32 m = smn[0], M = smx[0];
#pragma unroll
    for (int w = 1; w < 4; ++w) {
      if (smn[w] < m) m = smn[w];
      if (smx[w] > M) M = smx[w];
    }
    atomicMin(&gmm[0], m);
    atomicMax(&gmm[1], M);
  }
}

__device__ inline u32 bucket_of(u32 sb, u32 minv, u32 range) {
  return (u32)(((u64)(sb - minv) << 14) / ((u64)range + 1ull));   // 16384 buckets
}

// ---- K3: bucket histogram ----
__global__ __launch_bounds__(256) void hist_kernel(const u64* __restrict__ keysA,
                                                   const u32* __restrict__ gmm,
                                                   u32* __restrict__ ghist, int E) {
  int e = blockIdx.x * 256 + threadIdx.x;
  if (e >= E) return;
  u32 minv = gmm[0], range = gmm[1] - minv;
  u32 b = bucket_of((u32)(keysA[e] >> 32), minv, range);
  atomicAdd(&ghist[b], 1u);
}

// ---- K4: scan of 16384 bucket counts ----
__global__ __launch_bounds__(1024) void scan16k_kernel(const u32* __restrict__ ghist,
                                                       u32* __restrict__ starts,
                                                       u32* __restrict__ cursor, int E) {
  __shared__ u32 wsum[16];
  int tid = threadIdx.x;
  int lane = tid & 63, wv = tid >> 6;
  u32 loc[16];
  u32 s = 0;
#pragma unroll
  for (int i = 0; i < 16; ++i) { loc[i] = ghist[tid * 16 + i]; s += loc[i]; }
  u32 inc = s;
#pragma unroll
  for (int d = 1; d < 64; d <<= 1) {
    u32 t = __shfl_up(inc, d);
    if (lane >= d) inc += t;
  }
  if (lane == 63) wsum[wv] = inc;
  __syncthreads();
  if (tid == 0) {
    u32 r = 0;
#pragma unroll
    for (int w = 0; w < 16; ++w) { u32 t = wsum[w]; wsum[w] = r; r += t; }
  }
  __syncthreads();
  u32 run = wsum[wv] + (inc - s);
#pragma unroll
  for (int i = 0; i < 16; ++i) {
    starts[tid * 16 + i] = run;
    cursor[tid * 16 + i] = run;
    run += loc[i];
  }
  if (tid == 0) starts[16384] = (u32)E;
}

// ---- K5: scatter keys into bucket slots ----
__global__ __launch_bounds__(256) void scatter_kernel(const u64* __restrict__ keysA,
                                                      const u32* __restrict__ gmm,
                                                      u32* __restrict__ cursor,
                                                      u64* __restrict__ keysB, int E) {
  int e = blockIdx.x * 256 + threadIdx.x;
  if (e >= E) return;
  u64 key = keysA[e];
  u32 minv = gmm[0], range = gmm[1] - minv;
  u32 b = bucket_of((u32)(key >> 32), minv, range);
  u32 pos = atomicAdd(&cursor[b], 1u);
  keysB[pos] = key;
}

// ---- K6: per-bucket 128-elem bitonic sort (1 wave/bucket) + pack write ----
__global__ __launch_bounds__(256) void bucketsort_kernel(const u64* __restrict__ keysB,
                                                         const u32* __restrict__ starts,
                                                         const int* __restrict__ edges,
                                                         const u8* __restrict__ bnd,
                                                         u64* __restrict__ pack,
                                                         int E, int V, int NpadB) {
  int tid = threadIdx.x;
  int lane = tid & 63;
  int w = blockIdx.x * 4 + (tid >> 6);           // bucket id
  u32 start = starts[w];
  int cnt = (int)(starts[w + 1] - start);
  if (cnt > 128) cnt = 128;                      // safety clamp (P ~ 0)
  u64 k0 = (lane < cnt) ? keysB[start + lane] : ~0ull;
  u64 k1 = (64 + lane < cnt) ? keysB[start + 64 + lane] : ~0ull;
  int idx0 = lane * 2, idx1 = lane * 2 + 1;
#pragma unroll
  for (int k = 2; k <= 128; k <<= 1) {
#pragma unroll
    for (int j = 64; j >= 1; j >>= 1) {
      if (j > k / 2) continue;
      if (j >= 2) {
        int lj = j >> 1;
        u64 p0 = __shfl_xor(k0, lj);
        u64 p1 = __shfl_xor(k1, lj);
        bool keepMin0 = (((idx0 & j) == 0) == ((idx0 & k) == 0));
        k0 = keepMin0 ? (k0 < p0 ? k0 : p0) : (k0 > p0 ? k0 : p0);
        k1 = keepMin0 ? (k1 < p1 ? k1 : p1) : (k1 > p1 ? k1 : p1);
      } else {
        bool up = ((idx0 & k) == 0);
        u64 mn = (k0 < k1) ? k0 : k1;
        u64 mx = (k0 < k1) ? k1 : k0;
        k0 = up ? mn : mx;
        k1 = up ? mx : mn;
      }
    }
  }
  if (idx0 < cnt) {
    u32 id = (u32)k0;
    int vv0 = edges[id], vv1 = edges[E + id];
    pack[start + idx0] = (u64)(u32)(vv0 | (vv1 << 16)) | ((u64)bnd[id] << 32);
  }
  if (idx1 < cnt) {
    u32 id = (u32)k1;
    int vv0 = edges[id], vv1 = edges[E + id];
    pack[start + idx1] = (u64)(u32)(vv0 | (vv1 << 16)) | ((u64)bnd[id] << 32);
  }
  // sentinel tail [E, NpadB): nb=1 (never kills), verts in [V, V+512)
  int g = blockIdx.x * 256 + tid;
  int i = E + g;
  if (i < NpadB) {
    u32 sv0 = (u32)V + (((u32)i & 255u) << 1);
    pack[i] = (u64)(sv0 | ((sv0 + 1) << 16)) | (1ull << 32);
  }
}

// ---- K7: exact greedy collapse, ordered 4096-edge batches + in-reg peel ---
// R12/R13-verified decision logic; 1024 threads x 4 slots (pos = s*1024+tid).
// Version-tagged tUK entries (R15-verified): u16 = [15:13] verTag |
// [12:1] pos | [0] isUnd, verTag = 6-(round%7), DECREASING -> stale entries
// lose the CAS-min; readers validate tag else treat as empty.
// NEW vs R15: no full per-batch wipes. Only entries ever written are the
// v1s of this batch's edges; each thread resets its 4 v1 slots at batch end
// and at verTag cycle wrap (4 stores vs 25). One full wipe at kernel start.
__device__ inline void lds_min_u16(u16* tarr, int idx, u16 val) {
  u32* w = (u32*)(tarr + (idx & ~1));
  int sh = (idx & 1) * 16;
  u32 old = *w;
  while (true) {
    u32 cur = (old >> sh) & 0xffffu;
    if ((u32)val >= cur) break;
    u32 nv = (old & ~(0xffffu << sh)) | ((u32)val << sh);
    u32 prev = atomicCAS(w, old, nv);
    if (prev == old) break;
    old = prev;
  }
}

#define TPB 1024
#define SLOTS 4
#define NBAT 4096

__global__ __launch_bounds__(1024) void batch_kernel(const u64* __restrict__ pack,
                                                     const int* __restrict__ tgt,
                                                     float* __restrict__ out,
                                                     int V, int E, int NpadB) {
  __shared__ u16 tUK[50560];     // 101 KB; covers sentinel verts < V+512
  __shared__ u32 alive[1600];
  __shared__ u32 wred[65];
  __shared__ u32 misc[4];
  int tid = threadIdx.x;
  int lane = tid & 63, wv = tid >> 6;
  for (int i = tid; i < 1600; i += TPB) alive[i] = 0xFFFFFFFFu;
  for (int i = tid; i < 25280; i += TPB) ((u32*)tUK)[i] = 0xFFFFFFFFu;
  if (tid < 4) misc[tid] = 0u;
  int target = tgt[0];
  int needed = V - target; if (needed < 0) needed = 0;
  int remaining = needed;
  int nbatch = NpadB / NBAT;
  u64 pk[SLOTS], pn[SLOTS];
#pragma unroll
  for (int s = 0; s < SLOTS; ++s) pk[s] = pack[s * TPB + tid];
  __syncthreads();                                       // init wipe visible
  for (int b = 0; b < nbatch; ++b) {
    if (remaining <= 0) break;
    const u64* np = pack + (size_t)((b + 1 < nbatch) ? (b + 1) : b) * NBAT;
#pragma unroll
    for (int s = 0; s < SLOTS; ++s) pn[s] = np[s * TPB + tid];
    // ---- init status masks from current alive ----
    u32 und = 0, kill = 0;
#pragma unroll
    for (int s = 0; s < SLOTS; ++s) {
      int v0 = (int)(pk[s] & 0xffff), v1 = (int)((pk[s] >> 16) & 0xffff);
      int nb_ = (int)((pk[s] >> 32) & 1);
      int a0 = (int)((alive[v0 >> 5] >> (v0 & 31)) & 1);
      int a1 = (int)((alive[v1 >> 5] >> (v1 & 31)) & 1);
      und |= (u32)(a0 & a1 & (nb_ ^ 1)) << s;
    }
    // ---- peel rounds: 2 barriers each ----
    int rc = 0;
    for (int r = 0; r < 4200; ++r) {
      u32 tag = (u32)(6 - rc);
#pragma unroll
      for (int s = 0; s < SLOTS; ++s) {
        if ((und | kill) & (1u << s)) {
          int v1 = (int)((pk[s] >> 16) & 0xffff);
          u32 pos = (u32)(s * TPB + tid);
          lds_min_u16(tUK, v1, (u16)((tag << 13) | (pos << 1) | ((und >> s) & 1)));
        }
      }
      __syncthreads();                                   // B1: posts visible
#pragma unroll
      for (int s = 0; s < SLOTS; ++s) {
        if (und & (1u << s)) {
          int v0 = (int)(pk[s] & 0xffff), v1 = (int)((pk[s] >> 16) & 0xffff);
          u32 my = (tag << 13) | (((u32)(s * TPB + tid)) << 1) | 1u;
          u32 raw0 = (u32)tUK[v0], raw1 = (u32)tUK[v1];
          u32 b0v = (v0 == v1) ? 0xFFFFu : ((raw0 >> 13) == tag ? raw0 : 0xFFFFu);
          u32 b1v = ((raw1 >> 13) == tag) ? raw1 : 0xFFFFu;
          int ek = (int)(((b0v < my) & ((b0v & 1u) ^ 1u)) |
                         ((b1v < my) & ((b1v & 1u) ^ 1u)));
          int nk = (int)(b0v > my) & (int)(b1v == my) & (ek ^ 1);
          kill |= (u32)nk << s;
          if (nk | ek) und &= ~(1u << s);
        }
      }
      u64 au = __ballot(und != 0u);
      if (lane == 0 && au) atomicOr(&misc[r & 3], 1u);
      if (tid == 0) misc[(r + 2) & 3] = 0u;              // recycle slot r+2
      __syncthreads();                                   // B2: reads done
      u32 anyu = misc[r & 3];
      if (anyu == 0u) break;
      if (++rc == 7) {                                   // verTag cycle wrap
#pragma unroll
        for (int s = 0; s < SLOTS; ++s) {                // touched reset (4 stores)
          int v1 = (int)((pk[s] >> 16) & 0xffff);
          tUK[v1] = 0xFFFF;
        }
        __syncthreads();                                 // B3 (rare): resets visible
        rc = 0;
      }
    }
    // ---- batch-end touched reset (all tUK reads done after final B2) ----
#pragma unroll
    for (int s = 0; s < SLOTS; ++s) {
      int v1 = (int)((pk[s] >> 16) & 0xffff);
      tUK[v1] = 0xFFFF;
    }
    // ---- rank kills in position order, apply first `remaining` ----
#pragma unroll
    for (int s = 0; s < SLOTS; ++s) {
      u64 km = __ballot((kill >> s) & 1);
      if (lane == 0) wred[s * 16 + wv] = (u32)__popcll(km);
    }
    if (tid < 4) misc[tid] = 0u;                         // clean for next batch
    __syncthreads();                                     // B4: wred + resets visible
    if (tid == 0) {
      u32 run = 0;
      for (int i = 0; i < 64; ++i) { u32 t2 = wred[i]; wred[i] = run; run += t2; }
      wred[64] = run;
    }
    __syncthreads();                                     // B5
    u32 K = wred[64];
#pragma unroll
    for (int s = 0; s < SLOTS; ++s) {
      u64 km = __ballot((kill >> s) & 1);
      if ((kill >> s) & 1) {
        u32 rank = wred[s * 16 + wv] + (u32)__popcll(km & ((1ull << lane) - 1ull));
        if (rank < (u32)remaining) {
          int v1 = (int)((pk[s] >> 16) & 0xffff);
          atomicAnd(&alive[v1 >> 5], ~(1u << (v1 & 31)));
        }
      }
    }
    remaining -= (int)((K < (u32)remaining) ? K : (u32)remaining);
    __syncthreads();                                     // B6: applies visible
#pragma unroll
    for (int s = 0; s < SLOTS; ++s) pk[s] = pn[s];
  }
  __syncthreads();                                       // final applies visible
  // ---- fused expand: write float mask + count directly ----
  for (int i = tid; i < V; i += TPB)
    out[E + i] = ((alive[i >> 5] >> (i & 31)) & 1) ? 1.0f : 0.0f;
  if (tid == 0) out[E + V] = (float)(V - (needed - remaining));
}

extern "C" void kernel_launch(void* const* d_in, const int* in_sizes, int n_in,
                              void* d_out, int out_size, void* d_ws, size_t ws_size,
                              hipStream_t stream) {
  const float* image = (const float*)d_in[0];
  const float* vs    = (const float*)d_in[1];
  const int*   edges = (const int*)d_in[2];
  const int*   tgt   = (const int*)d_in[3];
  int V = in_sizes[1] / 2;                 // 50000
  int E = in_sizes[2] / 2;                 // 150000
  int NpadB = ((E + NBAT - 1) / NBAT) * NBAT;   // 151552 (37 x 4096)

  char* ws = (char*)d_ws;
  size_t o = 0;
  u64* keysA  = (u64*)(ws + o); o += (size_t)E * 8;
  u64* keysB  = (u64*)(ws + o); o += (size_t)E * 8;
  u64* pack   = (u64*)(ws + o); o += (size_t)NpadB * 8;
  float* nrm  = (float*)(ws + o); o += (size_t)V * 4;
  u8*  bnd    = (u8*)(ws + o);  o += (size_t)E;
  o = (o + 255) & ~(size_t)255;
  u32* ghist  = (u32*)(ws + o); o += 16384 * 4;
  u32* starts = (u32*)(ws + o); o += 16385 * 4;
  u32* cursor = (u32*)(ws + o); o += 16384 * 4;
  u32* gmm    = (u32*)(ws + o); o += 256;
  float* out = (float*)d_out;

  int eb = (E + 255) / 256;
  vnorm_kernel<<<dim3((2 * V + 255) / 256), dim3(256), 0, stream>>>(image, nrm, ghist, gmm, V);
  edge_kernel<<<dim3(eb), dim3(256), 0, stream>>>(nrm, vs, edges, keysA, bnd, out, gmm, E);
  hist_kernel<<<dim3(eb), dim3(256), 0, stream>>>(keysA, gmm, ghist, E);
  scan16k_kernel<<<dim3(1), dim3(1024), 0, stream>>>(ghist, starts, cursor, E);
  scatter_kernel<<<dim3(eb), dim3(256), 0, stream>>>(keysA, gmm, cursor, keysB, E);
  bucketsort_kernel<<<dim3(4096), dim3(256), 0, stream>>>(keysB, starts, edges, bnd,
                                                          pack, E, V, NpadB);
  batch_kernel<<<dim3(1), dim3(1024), 0, stream>>>(pack, tgt, out, V, E, NpadB);
}